// Round 14
// baseline (314.317 us; speedup 1.0000x reference)
//
#include <hip/hip_runtime.h>
#include <math.h>

typedef unsigned short u16;
typedef short s16;
typedef u16 u16x8 __attribute__((ext_vector_type(8)));
typedef u16 u16x4 __attribute__((ext_vector_type(4)));
typedef s16 s16x8 __attribute__((ext_vector_type(8)));
typedef float f32x4 __attribute__((ext_vector_type(4)));
typedef unsigned u32x4 __attribute__((ext_vector_type(4)));

__device__ __forceinline__ float b2f(u16 u) { return __uint_as_float(((unsigned)u) << 16); }
__device__ __forceinline__ u16 f2b(float f) {
  unsigned x = __float_as_uint(f);
  unsigned r = x + 0x7fffu + ((x >> 16) & 1u);
  return (u16)(r >> 16);
}
__device__ __forceinline__ unsigned cvtpk(float a, float b) {
  unsigned r;
  asm("v_cvt_pk_bf16_f32 %0, %1, %2" : "=v"(r) : "v"(a), "v"(b));
  return r;
}
union PkH { u32x4 w; s16x8 h; };
union Pk2 { unsigned w[2]; u16x4 h; };

#define SCALE 0.125f
#define SCLG2E 0.1803368801111137f   // 0.125 * log2(e); attn uses exp2
#define DM 512
#define NTOK 32768

typedef __attribute__((address_space(1))) unsigned int as1_u32;
typedef __attribute__((address_space(3))) unsigned int as3_u32;
__device__ __forceinline__ void gl2lds16(const u16* g, u16* s) {
  __builtin_amdgcn_global_load_lds((as1_u32*)g, (as3_u32*)s, 16, 0, 0);
}

// ---------------------------------------------------------------------------
// x fp32 -> bf16 + per-64-token column partial sums (for pooled means)
// ---------------------------------------------------------------------------
__global__ __launch_bounds__(256)
void conv_psum(const float* __restrict__ X, u16* __restrict__ Xb,
               float* __restrict__ Psum)
{
  __shared__ float ps[4][512];
  const int tid = threadIdx.x;
  const int c8 = (tid & 63) * 8;
  const int rg = tid >> 6;
  const size_t tok0 = (size_t)blockIdx.x * 64;
  f32x4 s0 = {0.f, 0.f, 0.f, 0.f}, s1 = {0.f, 0.f, 0.f, 0.f};
  for (int it = 0; it < 16; ++it) {
    const size_t tok = tok0 + it * 4 + rg;
    const float* xp = X + tok * DM + c8;
    f32x4 a = *(const f32x4*)xp;
    f32x4 b = *(const f32x4*)(xp + 4);
    Pk2 p0, p1;
    p0.w[0] = cvtpk(a[0], a[1]); p0.w[1] = cvtpk(a[2], a[3]);
    p1.w[0] = cvtpk(b[0], b[1]); p1.w[1] = cvtpk(b[2], b[3]);
    *(u16x4*)(Xb + tok * DM + c8)     = p0.h;
    *(u16x4*)(Xb + tok * DM + c8 + 4) = p1.h;
    s0 += a; s1 += b;
  }
  *(f32x4*)&ps[rg][c8]     = s0;
  *(f32x4*)&ps[rg][c8 + 4] = s1;
  __syncthreads();
#pragma unroll
  for (int i = 0; i < 2; ++i) {
    const int col = tid + i * 256;
    Psum[(size_t)blockIdx.x * DM + col] =
        ps[0][col] + ps[1][col] + ps[2][col] + ps[3][col];
  }
}

// ---------------------------------------------------------------------------
// pooled block means -> bf16
// ---------------------------------------------------------------------------
__global__ __launch_bounds__(256)
void pool_prep(const float* __restrict__ Psum, u16* __restrict__ PB)
{
  const int g = blockIdx.x, tid = threadIdx.x;
#pragma unroll
  for (int i = 0; i < 2; ++i) {
    const int col = tid + i * 256;
    float v = 0.f;
#pragma unroll
    for (int s = 0; s < 8; ++s) v += Psum[(size_t)(g * 8 + s) * DM + col];
    PB[(size_t)g * DM + col] = f2b(v * (1.f / 512.f));
  }
}

// ---------------------------------------------------------------------------
// transpose-convert 10 weight matrices -> Wt [n][k] bf16
// ---------------------------------------------------------------------------
__global__ __launch_bounds__(256)
void trans_w(const float* w0, const float* w1, const float* w2, const float* w3,
             const float* w4, const float* w5, const float* w6, const float* w7,
             const float* w8, const float* w9, u16* __restrict__ WT)
{
  __shared__ float t[32][33];
  const int z = blockIdx.z;
  const float* W = (z == 0) ? w0 : (z == 1) ? w1 : (z == 2) ? w2 : (z == 3) ? w3 :
                   (z == 4) ? w4 : (z == 5) ? w5 : (z == 6) ? w6 : (z == 7) ? w7 :
                   (z == 8) ? w8 : w9;
  u16* D = WT + (size_t)z * DM * DM;
  const int tx = threadIdx.x & 31, ty = threadIdx.x >> 5;
  const int n0 = blockIdx.x * 32, k0 = blockIdx.y * 32;
#pragma unroll
  for (int j = 0; j < 4; ++j)
    t[ty + j * 8][tx] = W[(size_t)(k0 + ty + j * 8) * DM + n0 + tx];
  __syncthreads();
#pragma unroll
  for (int j = 0; j < 4; ++j)
    D[(size_t)(n0 + ty + j * 8) * DM + k0 + tx] = f2b(t[tx][ty + j * 8]);
}

// ---------------------------------------------------------------------------
// direct fp32 -> bf16 convert (one 512x512 weight)
// ---------------------------------------------------------------------------
__global__ __launch_bounds__(256)
void conv_w(const float* __restrict__ W, u16* __restrict__ D)
{
  const size_t i = ((size_t)blockIdx.x * 256 + threadIdx.x) * 8;
  f32x4 a = *(const f32x4*)(W + i);
  f32x4 b = *(const f32x4*)(W + i + 4);
  Pk2 p0, p1;
  p0.w[0] = cvtpk(a[0], a[1]); p0.w[1] = cvtpk(a[2], a[3]);
  p1.w[0] = cvtpk(b[0], b[1]); p1.w[1] = cvtpk(b[2], b[3]);
  *(u16x4*)(D + i)     = p0.h;
  *(u16x4*)(D + i + 4) = p1.h;
}

// ---------------------------------------------------------------------------
// bc[j] = sum_k gb[k]*gate_w[koff+k][j] + (addb ? addb[j] : 0)
// ---------------------------------------------------------------------------
__global__ __launch_bounds__(256)
void bc_kernel(const float* __restrict__ gb, const float* __restrict__ gate_w,
               const float* __restrict__ addb, float* __restrict__ bc, int koff)
{
  __shared__ float red[8][32];
  const int tid = threadIdx.x;
  const int jj = tid & 31, part = tid >> 5;
  const int j = blockIdx.x * 32 + jj;
  float p = 0.f;
#pragma unroll
  for (int i = 0; i < 64; ++i) {
    const int k = part * 64 + i;
    p = fmaf(gb[k], gate_w[(size_t)(koff + k) * DM + j], p);
  }
  red[part][jj] = p;
  __syncthreads();
  if (tid < 32) {
    float v = addb ? addb[blockIdx.x * 32 + tid] : 0.f;
#pragma unroll
    for (int s = 0; s < 8; ++s) v += red[s][tid];
    bc[blockIdx.x * 32 + tid] = v;
  }
}

// ---------------------------------------------------------------------------
// MFMA GEMM (r12-proven), used only for the tiny weight-combine (EPI 3):
// 128x128 tile, BK=64, 2-phase dbuf, counted vmcnt(8), XOR bank swizzle.
// Cb[m][n] = bf16(sum_k A[m][k] * Wt[n][k])
// ---------------------------------------------------------------------------
__global__ __launch_bounds__(256)
void gemm_comb(const u16* __restrict__ A, const u16* __restrict__ Wt,
               u16* __restrict__ Cb)
{
  __shared__ u16 As[2][128 * 64];
  __shared__ u16 Bs[2][128 * 64];
  const int tid = threadIdx.x;
  const int w = tid >> 6, l = tid & 63;
  const int l15 = l & 15, gl = l >> 4;
  const int wm = w >> 1, wn = w & 1;
  const int m0 = blockIdx.y * 128, n0 = blockIdx.x * 128;

  const int srow = l >> 3;
  const int scol = ((l & 7) ^ (srow & 7)) * 8;
  const u16* Ag = A  + (size_t)(m0 + w * 32 + srow) * DM + scol;
  const u16* Bg = Wt + (size_t)(n0 + w * 32 + srow) * DM + scol;

  auto stage = [&](int t, int b) {
    const int k0 = t * 64;
#pragma unroll
    for (int c = 0; c < 4; ++c) {
      gl2lds16(Ag + (size_t)(c * 8) * DM + k0, &As[b][(w * 32 + c * 8) * 64]);
      gl2lds16(Bg + (size_t)(c * 8) * DM + k0, &Bs[b][(w * 32 + c * 8) * 64]);
    }
  };

  f32x4 acc[4][4];
#pragma unroll
  for (int i = 0; i < 4; ++i)
#pragma unroll
    for (int j = 0; j < 4; ++j) acc[i][j] = {0.f, 0.f, 0.f, 0.f};

  const int xorv = l15 & 7;
  stage(0, 0);
#pragma unroll
  for (int t = 0; t < 8; ++t) {
    if (t < 7) {
      stage(t + 1, (t + 1) & 1);
      asm volatile("s_waitcnt vmcnt(8)" ::: "memory");
    } else {
      asm volatile("s_waitcnt vmcnt(0)" ::: "memory");
    }
    __builtin_amdgcn_s_barrier();
    __builtin_amdgcn_sched_barrier(0);
    const int b = t & 1;
#pragma unroll
    for (int kd = 0; kd < 2; ++kd) {
      const int go = ((gl + 4 * kd) ^ xorv) * 8;
      s16x8 af[4], bfr[4];
#pragma unroll
      for (int f = 0; f < 4; ++f) {
        af[f]  = *(const s16x8*)&As[b][(wm * 64 + f * 16 + l15) * 64 + go];
        bfr[f] = *(const s16x8*)&Bs[b][(wn * 64 + f * 16 + l15) * 64 + go];
      }
#pragma unroll
      for (int fm = 0; fm < 4; ++fm)
#pragma unroll
        for (int fn = 0; fn < 4; ++fn)
          acc[fm][fn] = __builtin_amdgcn_mfma_f32_16x16x32_bf16(
              bfr[fn], af[fm], acc[fm][fn], 0, 0, 0);
    }
    __builtin_amdgcn_s_barrier();
  }

#pragma unroll
  for (int fm = 0; fm < 4; ++fm) {
    const int m = m0 + wm * 64 + fm * 16 + l15;
#pragma unroll
    for (int fn = 0; fn < 4; ++fn) {
      const int nb = n0 + wn * 64 + fn * 16 + gl * 4;
      Pk2 p;
      p.w[0] = cvtpk(acc[fm][fn][0], acc[fm][fn][1]);
      p.w[1] = cvtpk(acc[fm][fn][2], acc[fm][fn][3]);
      *(u16x4*)(Cb + (size_t)m * DM + nb) = p.h;
    }
  }
}

// ---------------------------------------------------------------------------
// FUSED Q/K/V GEMM, 3 sequential passes per block over the SAME (m0,n0) slab.
// Each pass = the r12-proven dbuf 8-step loop; A L2-hot for passes 2-3.
// Epilogues lifted from the r10-correctness-proven gemm_qkv.
// ---------------------------------------------------------------------------
__global__ __launch_bounds__(256)
void gemm_qkv3(const u16* __restrict__ A,
               const u16* __restrict__ WTq, const u16* __restrict__ WTk,
               const u16* __restrict__ WTv,
               const float* __restrict__ bq, const float* __restrict__ bk,
               const float* __restrict__ bv,
               u16* __restrict__ Qb, u16* __restrict__ Kb, u16* __restrict__ VT)
{
  __shared__ u16 As[2][128 * 64];
  __shared__ u16 Bs[2][128 * 64];
  const int tid = threadIdx.x;
  const int w = tid >> 6, l = tid & 63;
  const int l15 = l & 15, gl = l >> 4;
  const int wm = w >> 1, wn = w & 1;

  const int H = blockIdx.y * 4 + blockIdx.x;     // T1 remap, grid (4,256)
  const int xcd = H & 7, i = H >> 3;
  const int mt = xcd * 32 + (i >> 2);
  const int nt = i & 3;
  const int m0 = mt * 128, n0 = nt * 128;

  const int srow = l >> 3;
  const int scol = ((l & 7) ^ (srow & 7)) * 8;
  const u16* Ag = A + (size_t)(m0 + w * 32 + srow) * DM + scol;
  const int xorv = l15 & 7;

  for (int pass = 0; pass < 3; ++pass) {
    const u16* Wtp = (pass == 0) ? WTq : (pass == 1) ? WTk : WTv;
    const float* bias = (pass == 0) ? bq : (pass == 1) ? bk : bv;
    const u16* Bg = Wtp + (size_t)(n0 + w * 32 + srow) * DM + scol;

    auto stage = [&](int t, int b) {
      const int k0 = t * 64;
#pragma unroll
      for (int c = 0; c < 4; ++c) {
        gl2lds16(Ag + (size_t)(c * 8) * DM + k0, &As[b][(w * 32 + c * 8) * 64]);
        gl2lds16(Bg + (size_t)(c * 8) * DM + k0, &Bs[b][(w * 32 + c * 8) * 64]);
      }
    };

    f32x4 acc[4][4];
#pragma unroll
    for (int ii = 0; ii < 4; ++ii)
#pragma unroll
      for (int j = 0; j < 4; ++j) acc[ii][j] = {0.f, 0.f, 0.f, 0.f};

    stage(0, 0);
    if (pass < 2) {
#pragma unroll
      for (int t = 0; t < 8; ++t) {
        if (t < 7) {
          stage(t + 1, (t + 1) & 1);
          asm volatile("s_waitcnt vmcnt(8)" ::: "memory");
        } else {
          asm volatile("s_waitcnt vmcnt(0)" ::: "memory");
        }
        __builtin_amdgcn_s_barrier();
        __builtin_amdgcn_sched_barrier(0);
        const int b = t & 1;
#pragma unroll
        for (int kd = 0; kd < 2; ++kd) {
          const int go = ((gl + 4 * kd) ^ xorv) * 8;
          s16x8 af[4], bfr[4];
#pragma unroll
          for (int f = 0; f < 4; ++f) {
            af[f]  = *(const s16x8*)&As[b][(wm * 64 + f * 16 + l15) * 64 + go];
            bfr[f] = *(const s16x8*)&Bs[b][(wn * 64 + f * 16 + l15) * 64 + go];
          }
#pragma unroll
          for (int fm = 0; fm < 4; ++fm)
#pragma unroll
            for (int fn = 0; fn < 4; ++fn)
              acc[fm][fn] = __builtin_amdgcn_mfma_f32_16x16x32_bf16(
                  bfr[fn], af[fm], acc[fm][fn], 0, 0, 0);
        }
        __builtin_amdgcn_s_barrier();
      }
      // epilogue: rows = m, 4 consecutive n per reg
      u16* Cb = (pass == 0) ? Qb : Kb;
      const float sc = (pass == 0) ? SCLG2E : 1.0f;
#pragma unroll
      for (int fm = 0; fm < 4; ++fm) {
        const int m = m0 + wm * 64 + fm * 16 + l15;
#pragma unroll
        for (int fn = 0; fn < 4; ++fn) {
          const int nb = n0 + wn * 64 + fn * 16 + gl * 4;
          f32x4 b4 = *(const f32x4*)&bias[nb];
          f32x4 v = (acc[fm][fn] + b4) * sc;
          Pk2 p;
          p.w[0] = cvtpk(v[0], v[1]);
          p.w[1] = cvtpk(v[2], v[3]);
          *(u16x4*)(Cb + (size_t)m * DM + nb) = p.h;
        }
      }
    } else {
#pragma unroll
      for (int t = 0; t < 8; ++t) {
        if (t < 7) {
          stage(t + 1, (t + 1) & 1);
          asm volatile("s_waitcnt vmcnt(8)" ::: "memory");
        } else {
          asm volatile("s_waitcnt vmcnt(0)" ::: "memory");
        }
        __builtin_amdgcn_s_barrier();
        __builtin_amdgcn_sched_barrier(0);
        const int b = t & 1;
#pragma unroll
        for (int kd = 0; kd < 2; ++kd) {
          const int go = ((gl + 4 * kd) ^ xorv) * 8;
          s16x8 af[4], bfr[4];
#pragma unroll
          for (int f = 0; f < 4; ++f) {
            af[f]  = *(const s16x8*)&As[b][(wm * 64 + f * 16 + l15) * 64 + go];
            bfr[f] = *(const s16x8*)&Bs[b][(wn * 64 + f * 16 + l15) * 64 + go];
          }
#pragma unroll
          for (int fm = 0; fm < 4; ++fm)
#pragma unroll
            for (int fn = 0; fn < 4; ++fn)
              acc[fm][fn] = __builtin_amdgcn_mfma_f32_16x16x32_bf16(
                  af[fm], bfr[fn], acc[fm][fn], 0, 0, 0);
        }
        __builtin_amdgcn_s_barrier();
      }
      // epilogue: rows = m (4 consecutive per reg), permuted V^T store
#pragma unroll
      for (int fn = 0; fn < 4; ++fn) {
        const int n = n0 + wn * 64 + fn * 16 + l15;
        const float bn = bv[n];
        const int d = n & 63, ghn = n >> 6;
#pragma unroll
        for (int fm = 0; fm < 4; ++fm) {
          const int m = m0 + wm * 64 + fm * 16 + gl * 4;
          const int f = (m & 63) >> 4;
          const int pos = ((f >> 1) << 5) | (gl << 3) | ((f & 1) << 2);
          Pk2 p;
          p.w[0] = cvtpk(acc[fm][fn][0] + bn, acc[fm][fn][1] + bn);
          p.w[1] = cvtpk(acc[fm][fn][2] + bn, acc[fm][fn][3] + bn);
          *(u16x4*)(VT + ((size_t)(((m >> 9) * 8 + ghn) * 64 + d)) * 512
                       + ((m & 511) >> 6) * 64 + pos) = p.h;
        }
      }
    }
  }
}

// ---------------------------------------------------------------------------
// FUSED lo+gate GEMM: 2 passes over K from A = CTX.
// pass L: accL = CTX @ lo_w^T     pass Z: accZ = CTX @ Wc1 (= lo_w@gw1)
// out = g*(accL+lo_b) + (1-g)*GOUT, g = sigmoid(accZ + bc1 + GATEBLK)
// ---------------------------------------------------------------------------
__global__ __launch_bounds__(256)
void gemm_fuse(const u16* __restrict__ A, const u16* __restrict__ WtL,
               const u16* __restrict__ WtZ, const float* __restrict__ lo_b,
               const float* __restrict__ bc1, const float* __restrict__ GG,
               float* __restrict__ out)
{
  __shared__ u16 As[2][128 * 64];
  __shared__ u16 Bs[2][128 * 64];
  const int tid = threadIdx.x;
  const int w = tid >> 6, l = tid & 63;
  const int l15 = l & 15, gl = l >> 4;
  const int wm = w >> 1, wn = w & 1;

  const int H = blockIdx.y * 4 + blockIdx.x;     // T1 remap, grid (4,256)
  const int xcd = H & 7, i = H >> 3;
  const int mt = xcd * 32 + (i >> 2);
  const int nt = i & 3;
  const int m0 = mt * 128, n0 = nt * 128;

  const int srow = l >> 3;
  const int scol = ((l & 7) ^ (srow & 7)) * 8;
  const u16* Ag = A + (size_t)(m0 + w * 32 + srow) * DM + scol;
  const int xorv = l15 & 7;

  f32x4 accL[4][4], accZ[4][4];
#pragma unroll
  for (int ii = 0; ii < 4; ++ii)
#pragma unroll
    for (int j = 0; j < 4; ++j) {
      accL[ii][j] = {0.f, 0.f, 0.f, 0.f};
      accZ[ii][j] = {0.f, 0.f, 0.f, 0.f};
    }

  for (int pass = 0; pass < 2; ++pass) {
    const u16* Wtp = (pass == 0) ? WtL : WtZ;
    const u16* Bg = Wtp + (size_t)(n0 + w * 32 + srow) * DM + scol;
    auto stage = [&](int t, int b) {
      const int k0 = t * 64;
#pragma unroll
      for (int c = 0; c < 4; ++c) {
        gl2lds16(Ag + (size_t)(c * 8) * DM + k0, &As[b][(w * 32 + c * 8) * 64]);
        gl2lds16(Bg + (size_t)(c * 8) * DM + k0, &Bs[b][(w * 32 + c * 8) * 64]);
      }
    };
    stage(0, 0);
#pragma unroll
    for (int t = 0; t < 8; ++t) {
      if (t < 7) {
        stage(t + 1, (t + 1) & 1);
        asm volatile("s_waitcnt vmcnt(8)" ::: "memory");
      } else {
        asm volatile("s_waitcnt vmcnt(0)" ::: "memory");
      }
      __builtin_amdgcn_s_barrier();
      __builtin_amdgcn_sched_barrier(0);
      const int b = t & 1;
#pragma unroll
      for (int kd = 0; kd < 2; ++kd) {
        const int go = ((gl + 4 * kd) ^ xorv) * 8;
        s16x8 af[4], bfr[4];
#pragma unroll
        for (int f = 0; f < 4; ++f) {
          af[f]  = *(const s16x8*)&As[b][(wm * 64 + f * 16 + l15) * 64 + go];
          bfr[f] = *(const s16x8*)&Bs[b][(wn * 64 + f * 16 + l15) * 64 + go];
        }
        if (pass == 0) {
#pragma unroll
          for (int fm = 0; fm < 4; ++fm)
#pragma unroll
            for (int fn = 0; fn < 4; ++fn)
              accL[fm][fn] = __builtin_amdgcn_mfma_f32_16x16x32_bf16(
                  bfr[fn], af[fm], accL[fm][fn], 0, 0, 0);
        } else {
#pragma unroll
          for (int fm = 0; fm < 4; ++fm)
#pragma unroll
            for (int fn = 0; fn < 4; ++fn)
              accZ[fm][fn] = __builtin_amdgcn_mfma_f32_16x16x32_bf16(
                  bfr[fn], af[fm], accZ[fm][fn], 0, 0, 0);
        }
      }
      __builtin_amdgcn_s_barrier();
    }
  }

#pragma unroll
  for (int fm = 0; fm < 4; ++fm) {
    const int m = m0 + wm * 64 + fm * 16 + l15;
    const int brow = m >> 9;
#pragma unroll
    for (int fn = 0; fn < 4; ++fn) {
      const int nb = n0 + wn * 64 + fn * 16 + gl * 4;
      f32x4 lo = accL[fm][fn] + *(const f32x4*)&lo_b[nb];
      f32x4 z  = accZ[fm][fn] + *(const f32x4*)&bc1[nb]
                 + *(const f32x4*)&GG[(size_t)brow * 1024 + 512 + nb];
      f32x4 go4 = *(const f32x4*)&GG[(size_t)brow * 1024 + nb];
      f32x4 res;
#pragma unroll
      for (int r = 0; r < 4; ++r) {
        float g = 1.f / (1.f + __expf(-z[r]));
        res[r] = g * lo[r] + (1.f - g) * go4[r];
      }
      *(f32x4*)(out + (size_t)m * DM + nb) = res;
    }
  }
}

// ---------------------------------------------------------------------------
// Small MFMA GEMM (unchanged, validated)
// ---------------------------------------------------------------------------
__global__ __launch_bounds__(256)
void gemm64(const u16* __restrict__ A,
            const u16* B0, const u16* B1, const u16* B2,
            const float* b0, const float* b1, const float* b2,
            float* __restrict__ Out, int ldo)
{
  __shared__ u16 As[2][64 * 64];
  __shared__ u16 Bs[2][128 * 64];
  const int tid = threadIdx.x;
  const int w = tid >> 6, l = tid & 63;
  const int l15 = l & 15, gl = l >> 4;
  const int bx = blockIdx.x;
  const int grp = bx >> 2;
  const u16* Bt = ((grp == 0) ? B0 : (grp == 1) ? B1 : B2)
                  + (size_t)(bx & 3) * 128 * DM;
  const float* bias = (grp == 0) ? b0 : (grp == 1) ? b1 : b2;

  const int srow = l >> 3;
  const int scol = ((l & 7) ^ (srow & 7)) * 8;
  const u16* Ag = A  + (size_t)(w * 16 + srow) * DM + scol;
  const u16* Bg = Bt + (size_t)(w * 32 + srow) * DM + scol;

  auto stage = [&](int t, int b) {
    const int k0 = t * 64;
#pragma unroll
    for (int c = 0; c < 2; ++c)
      gl2lds16(Ag + (size_t)(c * 8) * DM + k0, &As[b][(w * 16 + c * 8) * 64]);
#pragma unroll
    for (int c = 0; c < 4; ++c)
      gl2lds16(Bg + (size_t)(c * 8) * DM + k0, &Bs[b][(w * 32 + c * 8) * 64]);
  };

  f32x4 acc[4][2];
#pragma unroll
  for (int i = 0; i < 4; ++i)
#pragma unroll
    for (int j = 0; j < 2; ++j) acc[i][j] = {0.f, 0.f, 0.f, 0.f};

  const int xorv = l15 & 7;
  stage(0, 0);
#pragma unroll
  for (int t = 0; t < 8; ++t) {
    if (t < 7) {
      stage(t + 1, (t + 1) & 1);
      asm volatile("s_waitcnt vmcnt(6)" ::: "memory");
    } else {
      asm volatile("s_waitcnt vmcnt(0)" ::: "memory");
    }
    __builtin_amdgcn_s_barrier();
    __builtin_amdgcn_sched_barrier(0);
    const int b = t & 1;
#pragma unroll
    for (int kd = 0; kd < 2; ++kd) {
      const int go = ((gl + 4 * kd) ^ xorv) * 8;
      s16x8 af[4], bfr[2];
#pragma unroll
      for (int f = 0; f < 4; ++f)
        af[f] = *(const s16x8*)&As[b][(f * 16 + l15) * 64 + go];
#pragma unroll
      for (int f = 0; f < 2; ++f)
        bfr[f] = *(const s16x8*)&Bs[b][(w * 32 + f * 16 + l15) * 64 + go];
#pragma unroll
      for (int fm = 0; fm < 4; ++fm)
#pragma unroll
        for (int fn = 0; fn < 2; ++fn)
          acc[fm][fn] = __builtin_amdgcn_mfma_f32_16x16x32_bf16(
              bfr[fn], af[fm], acc[fm][fn], 0, 0, 0);
    }
    __builtin_amdgcn_s_barrier();
  }

#pragma unroll
  for (int fm = 0; fm < 4; ++fm) {
    const int m = fm * 16 + l15;
#pragma unroll
    for (int fn = 0; fn < 2; ++fn) {
      const int nloc = w * 32 + fn * 16 + gl * 4;
      f32x4 b4 = *(const f32x4*)&bias[(bx & 3) * 128 + nloc];
      *(f32x4*)&Out[(size_t)m * ldo + bx * 128 + nloc] = acc[fm][fn] + b4;
    }
  }
}

// ---------------------------------------------------------------------------
// MFMA flash attention (r12-validated, unchanged)
// ---------------------------------------------------------------------------
__global__ __launch_bounds__(512, 4)
void attn_mfma(const u16* __restrict__ Q, const u16* __restrict__ K,
               const u16* __restrict__ VT, u16* __restrict__ CTX)
{
  __shared__ u16 Ks[64 * 64];
  __shared__ u16 VsT[64 * 64];
  const int tid = threadIdx.x;
  const int w = tid >> 6, l = tid & 63;
  const int l15 = l & 15, gl = l >> 4;
  const int g = blockIdx.x, h = blockIdx.y, qh = blockIdx.z;
  const int t0 = g * 512;
  const int fb = h * 64;
  const int q0 = t0 + qh * 256 + w * 32;
  const u16* VTb = VT + ((size_t)(g * 8 + h) * 64) * 512;

  s16x8 qf[2][2];
#pragma unroll
  for (int fq = 0; fq < 2; ++fq)
#pragma unroll
    for (int kd = 0; kd < 2; ++kd)
      qf[fq][kd] = *(const s16x8*)(Q + (size_t)(q0 + fq * 16 + l15) * DM
                                     + fb + gl * 8 + kd * 32);

  f32x4 o[2][4];
#pragma unroll
  for (int i = 0; i < 2; ++i)
#pragma unroll
    for (int j = 0; j < 4; ++j) o[i][j] = {0.f, 0.f, 0.f, 0.f};
  f32x4 psv[2] = {{0.f,0.f,0.f,0.f}, {0.f,0.f,0.f,0.f}};

  const int srow = tid >> 3;
  const int swg = ((tid & 7) ^ ((tid >> 3) & 7)) * 8;
  const u16* Kg = K + (size_t)(t0 + srow) * DM + fb + swg;
  const u16* Vg = VTb + (size_t)srow * 512 + swg;
  s16x8 kreg = *(const s16x8*)Kg;
  s16x8 vreg = *(const s16x8*)Vg;
  const int sw = l15 & 7;

  for (int kc = 0; kc < 8; ++kc) {
    __syncthreads();
    *(s16x8*)&Ks[tid * 8]  = kreg;
    *(s16x8*)&VsT[tid * 8] = vreg;
    __syncthreads();
    if (kc < 7) {
      kreg = *(const s16x8*)(Kg + (size_t)(kc + 1) * 64 * DM);
      vreg = *(const s16x8*)(Vg + (kc + 1) * 64);
    }

    f32x4 s[4][2];
#pragma unroll
    for (int i = 0; i < 4; ++i)
#pragma unroll
      for (int j = 0; j < 2; ++j) s[i][j] = {0.f, 0.f, 0.f, 0.f};
#pragma unroll
    for (int kd = 0; kd < 2; ++kd) {
      s16x8 kf[4];
#pragma unroll
      for (int fm = 0; fm < 4; ++fm)
        kf[fm] = *(const s16x8*)&Ks[(fm * 16 + l15) * 64 + ((gl + 4 * kd) ^ sw) * 8];
#pragma unroll
      for (int fm = 0; fm < 4; ++fm)
#pragma unroll
        for (int fq = 0; fq < 2; ++fq)
          s[fm][fq] = __builtin_amdgcn_mfma_f32_16x16x32_bf16(
              kf[fm], qf[fq][kd], s[fm][fq], 0, 0, 0);
    }

#pragma unroll
    for (int fq = 0; fq < 2; ++fq)
#pragma unroll
      for (int fm = 0; fm < 4; ++fm) {
#pragma unroll
        for (int r = 0; r < 4; ++r) s[fm][fq][r] = exp2f(s[fm][fq][r]);
        psv[fq] += s[fm][fq];
      }

    PkH pf[2][2];
#pragma unroll
    for (int ka = 0; ka < 2; ++ka)
#pragma unroll
      for (int fq = 0; fq < 2; ++fq) {
        pf[ka][fq].w[0] = cvtpk(s[2 * ka][fq][0], s[2 * ka][fq][1]);
        pf[ka][fq].w[1] = cvtpk(s[2 * ka][fq][2], s[2 * ka][fq][3]);
        pf[ka][fq].w[2] = cvtpk(s[2 * ka + 1][fq][0], s[2 * ka + 1][fq][1]);
        pf[ka][fq].w[3] = cvtpk(s[2 * ka + 1][fq][2], s[2 * ka + 1][fq][3]);
      }

#pragma unroll
    for (int ka = 0; ka < 2; ++ka)
#pragma unroll
      for (int fd = 0; fd < 4; ++fd) {
        s16x8 vf = *(const s16x8*)&VsT[(fd * 16 + l15) * 64 + ((ka * 4 + gl) ^ sw) * 8];
#pragma unroll
        for (int qm = 0; qm < 2; ++qm)
          o[qm][fd] = __builtin_amdgcn_mfma_f32_16x16x32_bf16(
              vf, pf[ka][qm].h, o[qm][fd], 0, 0, 0);
      }
  }

  float l_[2];
#pragma unroll
  for (int fq = 0; fq < 2; ++fq) {
    float t = (psv[fq][0] + psv[fq][1]) + (psv[fq][2] + psv[fq][3]);
    t += __shfl_xor(t, 16);
    t += __shfl_xor(t, 32);
    l_[fq] = t;
  }
#pragma unroll
  for (int qm = 0; qm < 2; ++qm) {
    const float inv = 1.f / l_[qm];
#pragma unroll
    for (int fd = 0; fd < 4; ++fd) {
      Pk2 p;
      p.w[0] = cvtpk(o[qm][fd][0] * inv, o[qm][fd][1] * inv);
      p.w[1] = cvtpk(o[qm][fd][2] * inv, o[qm][fd][3] * inv);
      *(u16x4*)(CTX + (size_t)(q0 + qm * 16 + l15) * DM + fb + fd * 16 + gl * 4) = p.h;
    }
  }
}

// ---------------------------------------------------------------------------
// Global attention over 16 pooled summaries per batch (fp32, tiny)
// ---------------------------------------------------------------------------
__global__ __launch_bounds__(256)
void gattn(const float* __restrict__ QKVg, u16* __restrict__ GlB)
{
  __shared__ float q[16][64], k[16][64], v[16][64];
  __shared__ float sc[16][16];
  const int bh = blockIdx.x;
  const int b = bh >> 3, h = bh & 7;
  const int tid = threadIdx.x;
  for (int idx = tid; idx < 1024; idx += 256) {
    const int n = idx >> 6, d = idx & 63;
    const size_t off = (size_t)(b * 16 + n) * 1536 + h * 64 + d;
    q[n][d] = QKVg[off]; k[n][d] = QKVg[off + 512]; v[n][d] = QKVg[off + 1024];
  }
  __syncthreads();
  {
    const int qq = tid >> 4, kk = tid & 15;
    float s = 0.f;
#pragma unroll
    for (int d = 0; d < 64; ++d) s = fmaf(q[qq][d], k[kk][d], s);
    sc[qq][kk] = s * SCALE;
  }
  __syncthreads();
  if (tid < 16) {
    float mx = -INFINITY;
#pragma unroll
    for (int j = 0; j < 16; ++j) mx = fmaxf(mx, sc[tid][j]);
    float e[16]; float sum = 0.f;
#pragma unroll
    for (int j = 0; j < 16; ++j) { e[j] = __expf(sc[tid][j] - mx); sum += e[j]; }
    const float inv = 1.f / sum;
#pragma unroll
    for (int j = 0; j < 16; ++j) sc[tid][j] = e[j] * inv;
  }
  __syncthreads();
  for (int idx = tid; idx < 1024; idx += 256) {
    const int qq = idx >> 6, d = idx & 63;
    float o = 0.f;
#pragma unroll
    for (int j = 0; j < 16; ++j) o = fmaf(sc[qq][j], v[j][d], o);
    GlB[(size_t)(b * 16 + qq) * DM + h * 64 + d] = f2b(o);
  }
}

// ---------------------------------------------------------------------------
extern "C" void kernel_launch(void* const* d_in, const int* in_sizes, int n_in,
                              void* d_out, int out_size, void* d_ws, size_t ws_size,
                              hipStream_t stream)
{
  const float* x      = (const float*)d_in[0];
  const float* lq_w   = (const float*)d_in[1];
  const float* lq_b   = (const float*)d_in[2];
  const float* lk_w   = (const float*)d_in[3];
  const float* lk_b   = (const float*)d_in[4];
  const float* lv_w   = (const float*)d_in[5];
  const float* lv_b   = (const float*)d_in[6];
  const float* lo_w   = (const float*)d_in[7];
  const float* lo_b   = (const float*)d_in[8];
  const float* gq_w   = (const float*)d_in[9];
  const float* gq_b   = (const float*)d_in[10];
  const float* gk_w   = (const float*)d_in[11];
  const float* gk_b   = (const float*)d_in[12];
  const float* gv_w   = (const float*)d_in[13];
  const float* gv_b   = (const float*)d_in[14];
  const float* go_w   = (const float*)d_in[15];
  const float* go_b   = (const float*)d_in[16];
  const float* gate_w = (const float*)d_in[17];
  const float* gate_b = (const float*)d_in[18];
  float* out = (float*)d_out;

  const size_t NE = (size_t)NTOK * DM;
  const size_t DD = (size_t)DM * DM;
  char* ws = (char*)d_ws;
  u16* Qb   = (u16*)ws;
  u16* Kb   = Qb + NE;
  u16* VT   = Kb + NE;
  u16* WT   = VT + NE;
  u16* goD  = WT + 10 * DD;
  u16* loD  = goD + DD;
  u16* WcT  = loD + DD;         // (go_w@gw2)^T
  u16* Wc1T = WcT + DD;         // (lo_w@gw1)^T
  u16* PB   = Wc1T + DD;
  u16* GlB  = PB + 64 * DM;
  float* scr  = (float*)(GlB + 64 * DM);
  float* Psum = scr;
  float* QKVg = Psum + 512 * DM;
  float* GG   = QKVg + (size_t)64 * 1536;
  float* bc   = GG + (size_t)64 * 1024;
  float* bc1  = bc + DM;
  u16* xb = (u16*)d_out;

  u16* WTq  = WT;
  u16* WTk  = WT + 1 * DD;
  u16* WTv  = WT + 2 * DD;
  u16* WTo  = WT + 3 * DD;
  u16* WTg  = WT + 4 * DD;      // gw1^T (gate_w rows 0..511)
  u16* WTgq = WT + 5 * DD;
  u16* WTgk = WT + 6 * DD;
  u16* WTgv = WT + 7 * DD;
  u16* WTgo = WT + 8 * DD;
  u16* WTg2 = WT + 9 * DD;      // gw2^T (gate_w rows 512..1023)

  conv_psum<<<512, 256, 0, stream>>>(x, xb, Psum);
  trans_w<<<dim3(16, 16, 10), 256, 0, stream>>>(
      lq_w, lk_w, lv_w, lo_w, gate_w, gq_w, gk_w, gv_w, go_w,
      gate_w + DD, WT);
  conv_w<<<128, 256, 0, stream>>>(go_w, goD);
  conv_w<<<128, 256, 0, stream>>>(lo_w, loD);
  bc_kernel<<<16, 256, 0, stream>>>(go_b, gate_w, gate_b, bc, 512);
  bc_kernel<<<16, 256, 0, stream>>>(lo_b, gate_w, nullptr, bc1, 0);
  pool_prep<<<64, 256, 0, stream>>>(Psum, PB);

  const dim3 bb(256);
  gemm_qkv3<<<dim3(4, 256), bb, 0, stream>>>(xb, WTq, WTk, WTv,
                                             lq_b, lk_b, lv_b, Qb, Kb, VT);
  gemm_comb<<<dim3(4, 4), bb, 0, stream>>>(WTg2, goD, WcT);
  gemm_comb<<<dim3(4, 4), bb, 0, stream>>>(WTg, loD, Wc1T);

  attn_mfma<<<dim3(64, 8, 2), 512, 0, stream>>>(Qb, Kb, VT, Qb /*CTX*/);

  gemm64<<<12, 256, 0, stream>>>(PB, WTgq, WTgk, WTgv, gq_b, gk_b, gv_b, QKVg, 1536);
  gattn<<<32, 256, 0, stream>>>(QKVg, GlB);
  gemm64<<<8, 256, 0, stream>>>(GlB, WTgo, WcT, WcT, go_b, bc, bc, GG, 1024);

  gemm_fuse<<<dim3(4, 256), bb, 0, stream>>>(Qb /*CTX*/, WTo, Wc1T, lo_b, bc1, GG, out);
}

// Round 15
// 248.322 us; speedup vs baseline: 1.2658x; 1.2658x over previous
//
#include <hip/hip_runtime.h>
#include <math.h>

typedef unsigned short u16;
typedef short s16;
typedef u16 u16x8 __attribute__((ext_vector_type(8)));
typedef u16 u16x4 __attribute__((ext_vector_type(4)));
typedef s16 s16x8 __attribute__((ext_vector_type(8)));
typedef float f32x4 __attribute__((ext_vector_type(4)));
typedef unsigned u32x4 __attribute__((ext_vector_type(4)));

__device__ __forceinline__ float b2f(u16 u) { return __uint_as_float(((unsigned)u) << 16); }
__device__ __forceinline__ u16 f2b(float f) {
  unsigned x = __float_as_uint(f);
  unsigned r = x + 0x7fffu + ((x >> 16) & 1u);
  return (u16)(r >> 16);
}
__device__ __forceinline__ unsigned cvtpk(float a, float b) {
  unsigned r;
  asm("v_cvt_pk_bf16_f32 %0, %1, %2" : "=v"(r) : "v"(a), "v"(b));
  return r;
}
union PkH { u32x4 w; s16x8 h; };
union Pk2 { unsigned w[2]; u16x4 h; };

#define SCALE 0.125f
#define SCLG2E 0.1803368801111137f   // 0.125 * log2(e); attn uses exp2
#define DM 512
#define NTOK 32768

typedef __attribute__((address_space(1))) unsigned int as1_u32;
typedef __attribute__((address_space(3))) unsigned int as3_u32;
__device__ __forceinline__ void gl2lds16(const u16* g, u16* s) {
  __builtin_amdgcn_global_load_lds((as1_u32*)g, (as3_u32*)s, 16, 0, 0);
}

// ---------------------------------------------------------------------------
// x fp32 -> bf16 + per-64-token column partial sums (for pooled means)
// ---------------------------------------------------------------------------
__global__ __launch_bounds__(256)
void conv_psum(const float* __restrict__ X, u16* __restrict__ Xb,
               float* __restrict__ Psum)
{
  __shared__ float ps[4][512];
  const int tid = threadIdx.x;
  const int c8 = (tid & 63) * 8;
  const int rg = tid >> 6;
  const size_t tok0 = (size_t)blockIdx.x * 64;
  f32x4 s0 = {0.f, 0.f, 0.f, 0.f}, s1 = {0.f, 0.f, 0.f, 0.f};
  for (int it = 0; it < 16; ++it) {
    const size_t tok = tok0 + it * 4 + rg;
    const float* xp = X + tok * DM + c8;
    f32x4 a = *(const f32x4*)xp;
    f32x4 b = *(const f32x4*)(xp + 4);
    Pk2 p0, p1;
    p0.w[0] = cvtpk(a[0], a[1]); p0.w[1] = cvtpk(a[2], a[3]);
    p1.w[0] = cvtpk(b[0], b[1]); p1.w[1] = cvtpk(b[2], b[3]);
    *(u16x4*)(Xb + tok * DM + c8)     = p0.h;
    *(u16x4*)(Xb + tok * DM + c8 + 4) = p1.h;
    s0 += a; s1 += b;
  }
  *(f32x4*)&ps[rg][c8]     = s0;
  *(f32x4*)&ps[rg][c8 + 4] = s1;
  __syncthreads();
#pragma unroll
  for (int i = 0; i < 2; ++i) {
    const int col = tid + i * 256;
    Psum[(size_t)blockIdx.x * DM + col] =
        ps[0][col] + ps[1][col] + ps[2][col] + ps[3][col];
  }
}

// ---------------------------------------------------------------------------
// pooled block means -> bf16
// ---------------------------------------------------------------------------
__global__ __launch_bounds__(256)
void pool_prep(const float* __restrict__ Psum, u16* __restrict__ PB)
{
  const int g = blockIdx.x, tid = threadIdx.x;
#pragma unroll
  for (int i = 0; i < 2; ++i) {
    const int col = tid + i * 256;
    float v = 0.f;
#pragma unroll
    for (int s = 0; s < 8; ++s) v += Psum[(size_t)(g * 8 + s) * DM + col];
    PB[(size_t)g * DM + col] = f2b(v * (1.f / 512.f));
  }
}

// ---------------------------------------------------------------------------
// transpose-convert 10 weight matrices -> Wt [n][k] bf16
// ---------------------------------------------------------------------------
__global__ __launch_bounds__(256)
void trans_w(const float* w0, const float* w1, const float* w2, const float* w3,
             const float* w4, const float* w5, const float* w6, const float* w7,
             const float* w8, const float* w9, u16* __restrict__ WT)
{
  __shared__ float t[32][33];
  const int z = blockIdx.z;
  const float* W = (z == 0) ? w0 : (z == 1) ? w1 : (z == 2) ? w2 : (z == 3) ? w3 :
                   (z == 4) ? w4 : (z == 5) ? w5 : (z == 6) ? w6 : (z == 7) ? w7 :
                   (z == 8) ? w8 : w9;
  u16* D = WT + (size_t)z * DM * DM;
  const int tx = threadIdx.x & 31, ty = threadIdx.x >> 5;
  const int n0 = blockIdx.x * 32, k0 = blockIdx.y * 32;
#pragma unroll
  for (int j = 0; j < 4; ++j)
    t[ty + j * 8][tx] = W[(size_t)(k0 + ty + j * 8) * DM + n0 + tx];
  __syncthreads();
#pragma unroll
  for (int j = 0; j < 4; ++j)
    D[(size_t)(n0 + ty + j * 8) * DM + k0 + tx] = f2b(t[tx][ty + j * 8]);
}

// ---------------------------------------------------------------------------
// direct fp32 -> bf16 convert (go_w)
// ---------------------------------------------------------------------------
__global__ __launch_bounds__(256)
void conv_w(const float* __restrict__ W, u16* __restrict__ D)
{
  const size_t i = ((size_t)blockIdx.x * 256 + threadIdx.x) * 8;
  f32x4 a = *(const f32x4*)(W + i);
  f32x4 b = *(const f32x4*)(W + i + 4);
  Pk2 p0, p1;
  p0.w[0] = cvtpk(a[0], a[1]); p0.w[1] = cvtpk(a[2], a[3]);
  p1.w[0] = cvtpk(b[0], b[1]); p1.w[1] = cvtpk(b[2], b[3]);
  *(u16x4*)(D + i)     = p0.h;
  *(u16x4*)(D + i + 4) = p1.h;
}

// ---------------------------------------------------------------------------
// bc[j] = sum_k go_b[k]*gw2[k][j] + gate_b[j]
// ---------------------------------------------------------------------------
__global__ __launch_bounds__(256)
void bc_kernel(const float* __restrict__ go_b, const float* __restrict__ gate_w,
               const float* __restrict__ gate_b, float* __restrict__ bc)
{
  __shared__ float red[8][32];
  const int tid = threadIdx.x;
  const int jj = tid & 31, part = tid >> 5;
  const int j = blockIdx.x * 32 + jj;
  float p = 0.f;
#pragma unroll
  for (int i = 0; i < 64; ++i) {
    const int k = part * 64 + i;
    p = fmaf(go_b[k], gate_w[(size_t)(512 + k) * DM + j], p);
  }
  red[part][jj] = p;
  __syncthreads();
  if (tid < 32) {
    float v = gate_b[blockIdx.x * 32 + tid];
#pragma unroll
    for (int s = 0; s < 8; ++s) v += red[s][tid];
    bc[blockIdx.x * 32 + tid] = v;
  }
}

// ---------------------------------------------------------------------------
// MFMA GEMM (r12-proven): 128x128 tile, BK=64, 2-phase dbuf, counted vmcnt(8),
// XOR bank swizzle, T1 XCD remap when grid is (4,256).
// EPI 0: Cb = bf16((acc+bias)*outscale)   EPI 1: gate epilogue
// EPI 2: permuted V^T store              EPI 3: Cb = bf16(acc)
// ---------------------------------------------------------------------------
template<int EPI>
__global__ __launch_bounds__(256)
void gemm_mfma(const u16* __restrict__ A, const u16* __restrict__ Wt,
               const float* __restrict__ bias, u16* __restrict__ Cb,
               float* __restrict__ Cf, float outscale,
               const float* __restrict__ GG)
{
  __shared__ u16 As[2][128 * 64];
  __shared__ u16 Bs[2][128 * 64];
  const int tid = threadIdx.x;
  const int w = tid >> 6, l = tid & 63;
  const int l15 = l & 15, gl = l >> 4;
  const int wm = w >> 1, wn = w & 1;

  int mt, nt;
  if (gridDim.y == 256) {           // T1 remap (bijective)
    const int H = blockIdx.y * 4 + blockIdx.x;
    const int xcd = H & 7, i = H >> 3;
    mt = xcd * 32 + (i >> 2);
    nt = i & 3;
  } else {
    mt = blockIdx.y; nt = blockIdx.x;
  }
  const int m0 = mt * 128, n0 = nt * 128;

  const int srow = l >> 3;
  const int scol = ((l & 7) ^ (srow & 7)) * 8;
  const u16* Ag = A  + (size_t)(m0 + w * 32 + srow) * DM + scol;
  const u16* Bg = Wt + (size_t)(n0 + w * 32 + srow) * DM + scol;

  auto stage = [&](int t, int b) {
    const int k0 = t * 64;
#pragma unroll
    for (int c = 0; c < 4; ++c) {
      gl2lds16(Ag + (size_t)(c * 8) * DM + k0, &As[b][(w * 32 + c * 8) * 64]);
      gl2lds16(Bg + (size_t)(c * 8) * DM + k0, &Bs[b][(w * 32 + c * 8) * 64]);
    }
  };

  f32x4 acc[4][4];
#pragma unroll
  for (int i = 0; i < 4; ++i)
#pragma unroll
    for (int j = 0; j < 4; ++j) acc[i][j] = {0.f, 0.f, 0.f, 0.f};

  const int xorv = l15 & 7;
  stage(0, 0);
#pragma unroll
  for (int t = 0; t < 8; ++t) {
    if (t < 7) {
      stage(t + 1, (t + 1) & 1);
      asm volatile("s_waitcnt vmcnt(8)" ::: "memory");
    } else {
      asm volatile("s_waitcnt vmcnt(0)" ::: "memory");
    }
    __builtin_amdgcn_s_barrier();
    __builtin_amdgcn_sched_barrier(0);
    const int b = t & 1;
#pragma unroll
    for (int kd = 0; kd < 2; ++kd) {
      const int go = ((gl + 4 * kd) ^ xorv) * 8;
      s16x8 af[4], bfr[4];
#pragma unroll
      for (int f = 0; f < 4; ++f) {
        af[f]  = *(const s16x8*)&As[b][(wm * 64 + f * 16 + l15) * 64 + go];
        bfr[f] = *(const s16x8*)&Bs[b][(wn * 64 + f * 16 + l15) * 64 + go];
      }
#pragma unroll
      for (int fm = 0; fm < 4; ++fm)
#pragma unroll
        for (int fn = 0; fn < 4; ++fn) {
          if (EPI == 2)
            acc[fm][fn] = __builtin_amdgcn_mfma_f32_16x16x32_bf16(
                af[fm], bfr[fn], acc[fm][fn], 0, 0, 0);
          else
            acc[fm][fn] = __builtin_amdgcn_mfma_f32_16x16x32_bf16(
                bfr[fn], af[fm], acc[fm][fn], 0, 0, 0);
        }
    }
    __builtin_amdgcn_s_barrier();
  }

  if (EPI == 2) {
#pragma unroll
    for (int fn = 0; fn < 4; ++fn) {
      const int n = n0 + wn * 64 + fn * 16 + l15;
      const float bn = bias[n];
      const int d = n & 63, ghn = n >> 6;
#pragma unroll
      for (int fm = 0; fm < 4; ++fm) {
        const int m = m0 + wm * 64 + fm * 16 + gl * 4;
        const int f = (m & 63) >> 4;
        const int pos = ((f >> 1) << 5) | (gl << 3) | ((f & 1) << 2);
        Pk2 p;
        p.w[0] = cvtpk(acc[fm][fn][0] + bn, acc[fm][fn][1] + bn);
        p.w[1] = cvtpk(acc[fm][fn][2] + bn, acc[fm][fn][3] + bn);
        *(u16x4*)(Cb + ((size_t)(((m >> 9) * 8 + ghn) * 64 + d)) * 512
                     + ((m & 511) >> 6) * 64 + pos) = p.h;
      }
    }
  } else {
#pragma unroll
    for (int fm = 0; fm < 4; ++fm) {
      const int m = m0 + wm * 64 + fm * 16 + l15;
      const int brow = m >> 9;
#pragma unroll
      for (int fn = 0; fn < 4; ++fn) {
        const int nb = n0 + wn * 64 + fn * 16 + gl * 4;
        if (EPI == 0) {
          f32x4 b4 = *(const f32x4*)&bias[nb];
          f32x4 v = (acc[fm][fn] + b4) * outscale;
          Pk2 p;
          p.w[0] = cvtpk(v[0], v[1]);
          p.w[1] = cvtpk(v[2], v[3]);
          *(u16x4*)(Cb + (size_t)m * DM + nb) = p.h;
        } else if (EPI == 3) {
          Pk2 p;
          p.w[0] = cvtpk(acc[fm][fn][0], acc[fm][fn][1]);
          p.w[1] = cvtpk(acc[fm][fn][2], acc[fm][fn][3]);
          *(u16x4*)(Cb + (size_t)m * DM + nb) = p.h;
        } else {
          f32x4 z = acc[fm][fn] + *(const f32x4*)&GG[(size_t)brow * 1024 + 512 + nb];
          u16x4 lo4 = *(const u16x4*)(A + (size_t)m * DM + nb);
          f32x4 go4 = *(const f32x4*)&GG[(size_t)brow * 1024 + nb];
          f32x4 res;
#pragma unroll
          for (int r = 0; r < 4; ++r) {
            float g = 1.f / (1.f + __expf(-z[r]));
            res[r] = g * b2f(lo4[r]) + (1.f - g) * go4[r];
          }
          *(f32x4*)(Cf + (size_t)m * DM + nb) = res;
        }
      }
    }
  }
}

// ---------------------------------------------------------------------------
// Small MFMA GEMM (unchanged, validated)
// ---------------------------------------------------------------------------
__global__ __launch_bounds__(256)
void gemm64(const u16* __restrict__ A,
            const u16* B0, const u16* B1, const u16* B2,
            const float* b0, const float* b1, const float* b2,
            float* __restrict__ Out, int ldo)
{
  __shared__ u16 As[2][64 * 64];
  __shared__ u16 Bs[2][128 * 64];
  const int tid = threadIdx.x;
  const int w = tid >> 6, l = tid & 63;
  const int l15 = l & 15, gl = l >> 4;
  const int bx = blockIdx.x;
  const int grp = bx >> 2;
  const u16* Bt = ((grp == 0) ? B0 : (grp == 1) ? B1 : B2)
                  + (size_t)(bx & 3) * 128 * DM;
  const float* bias = (grp == 0) ? b0 : (grp == 1) ? b1 : b2;

  const int srow = l >> 3;
  const int scol = ((l & 7) ^ (srow & 7)) * 8;
  const u16* Ag = A  + (size_t)(w * 16 + srow) * DM + scol;
  const u16* Bg = Bt + (size_t)(w * 32 + srow) * DM + scol;

  auto stage = [&](int t, int b) {
    const int k0 = t * 64;
#pragma unroll
    for (int c = 0; c < 2; ++c)
      gl2lds16(Ag + (size_t)(c * 8) * DM + k0, &As[b][(w * 16 + c * 8) * 64]);
#pragma unroll
    for (int c = 0; c < 4; ++c)
      gl2lds16(Bg + (size_t)(c * 8) * DM + k0, &Bs[b][(w * 32 + c * 8) * 64]);
  };

  f32x4 acc[4][2];
#pragma unroll
  for (int i = 0; i < 4; ++i)
#pragma unroll
    for (int j = 0; j < 2; ++j) acc[i][j] = {0.f, 0.f, 0.f, 0.f};

  const int xorv = l15 & 7;
  stage(0, 0);
#pragma unroll
  for (int t = 0; t < 8; ++t) {
    if (t < 7) {
      stage(t + 1, (t + 1) & 1);
      asm volatile("s_waitcnt vmcnt(6)" ::: "memory");
    } else {
      asm volatile("s_waitcnt vmcnt(0)" ::: "memory");
    }
    __builtin_amdgcn_s_barrier();
    __builtin_amdgcn_sched_barrier(0);
    const int b = t & 1;
#pragma unroll
    for (int kd = 0; kd < 2; ++kd) {
      const int go = ((gl + 4 * kd) ^ xorv) * 8;
      s16x8 af[4], bfr[2];
#pragma unroll
      for (int f = 0; f < 4; ++f)
        af[f] = *(const s16x8*)&As[b][(f * 16 + l15) * 64 + go];
#pragma unroll
      for (int f = 0; f < 2; ++f)
        bfr[f] = *(const s16x8*)&Bs[b][(w * 32 + f * 16 + l15) * 64 + go];
#pragma unroll
      for (int fm = 0; fm < 4; ++fm)
#pragma unroll
        for (int fn = 0; fn < 2; ++fn)
          acc[fm][fn] = __builtin_amdgcn_mfma_f32_16x16x32_bf16(
              bfr[fn], af[fm], acc[fm][fn], 0, 0, 0);
    }
    __builtin_amdgcn_s_barrier();
  }

#pragma unroll
  for (int fm = 0; fm < 4; ++fm) {
    const int m = fm * 16 + l15;
#pragma unroll
    for (int fn = 0; fn < 2; ++fn) {
      const int nloc = w * 32 + fn * 16 + gl * 4;
      f32x4 b4 = *(const f32x4*)&bias[(bx & 3) * 128 + nloc];
      *(f32x4*)&Out[(size_t)m * ldo + bx * 128 + nloc] = acc[fm][fn] + b4;
    }
  }
}

// ---------------------------------------------------------------------------
// MFMA flash attention (r12-validated core) + T5 setprio around MFMA
// clusters (pure scheduler hint, no memory semantics -> numerically safe).
// ---------------------------------------------------------------------------
__global__ __launch_bounds__(512, 4)
void attn_mfma(const u16* __restrict__ Q, const u16* __restrict__ K,
               const u16* __restrict__ VT, u16* __restrict__ CTX)
{
  __shared__ u16 Ks[64 * 64];
  __shared__ u16 VsT[64 * 64];
  const int tid = threadIdx.x;
  const int w = tid >> 6, l = tid & 63;
  const int l15 = l & 15, gl = l >> 4;
  const int g = blockIdx.x, h = blockIdx.y, qh = blockIdx.z;
  const int t0 = g * 512;
  const int fb = h * 64;
  const int q0 = t0 + qh * 256 + w * 32;
  const u16* VTb = VT + ((size_t)(g * 8 + h) * 64) * 512;

  s16x8 qf[2][2];
#pragma unroll
  for (int fq = 0; fq < 2; ++fq)
#pragma unroll
    for (int kd = 0; kd < 2; ++kd)
      qf[fq][kd] = *(const s16x8*)(Q + (size_t)(q0 + fq * 16 + l15) * DM
                                     + fb + gl * 8 + kd * 32);

  f32x4 o[2][4];
#pragma unroll
  for (int i = 0; i < 2; ++i)
#pragma unroll
    for (int j = 0; j < 4; ++j) o[i][j] = {0.f, 0.f, 0.f, 0.f};
  f32x4 psv[2] = {{0.f,0.f,0.f,0.f}, {0.f,0.f,0.f,0.f}};

  const int srow = tid >> 3;
  const int swg = ((tid & 7) ^ ((tid >> 3) & 7)) * 8;
  const u16* Kg = K + (size_t)(t0 + srow) * DM + fb + swg;
  const u16* Vg = VTb + (size_t)srow * 512 + swg;
  s16x8 kreg = *(const s16x8*)Kg;
  s16x8 vreg = *(const s16x8*)Vg;
  const int sw = l15 & 7;

  for (int kc = 0; kc < 8; ++kc) {
    __syncthreads();
    *(s16x8*)&Ks[tid * 8]  = kreg;
    *(s16x8*)&VsT[tid * 8] = vreg;
    __syncthreads();
    if (kc < 7) {
      kreg = *(const s16x8*)(Kg + (size_t)(kc + 1) * 64 * DM);
      vreg = *(const s16x8*)(Vg + (kc + 1) * 64);
    }

    // S^T = K @ Q^T : lane holds S[key=fm*16+gl*4+r][q=fq*16+l15]
    f32x4 s[4][2];
#pragma unroll
    for (int i = 0; i < 4; ++i)
#pragma unroll
      for (int j = 0; j < 2; ++j) s[i][j] = {0.f, 0.f, 0.f, 0.f};
    __builtin_amdgcn_s_setprio(1);
#pragma unroll
    for (int kd = 0; kd < 2; ++kd) {
      s16x8 kf[4];
#pragma unroll
      for (int fm = 0; fm < 4; ++fm)
        kf[fm] = *(const s16x8*)&Ks[(fm * 16 + l15) * 64 + ((gl + 4 * kd) ^ sw) * 8];
#pragma unroll
      for (int fm = 0; fm < 4; ++fm)
#pragma unroll
        for (int fq = 0; fq < 2; ++fq)
          s[fm][fq] = __builtin_amdgcn_mfma_f32_16x16x32_bf16(
              kf[fm], qf[fq][kd], s[fm][fq], 0, 0, 0);
    }
    __builtin_amdgcn_s_setprio(0);

    // P = exp2(S); accumulate row-sum vector (deferred reduce)
#pragma unroll
    for (int fq = 0; fq < 2; ++fq)
#pragma unroll
      for (int fm = 0; fm < 4; ++fm) {
#pragma unroll
        for (int r = 0; r < 4; ++r) s[fm][fq][r] = exp2f(s[fm][fq][r]);
        psv[fq] += s[fm][fq];
      }

    // pack P -> bf16 fragments (keys (2ka+(j>>2))*16+gl*4+(j&3))
    PkH pf[2][2];
#pragma unroll
    for (int ka = 0; ka < 2; ++ka)
#pragma unroll
      for (int fq = 0; fq < 2; ++fq) {
        pf[ka][fq].w[0] = cvtpk(s[2 * ka][fq][0], s[2 * ka][fq][1]);
        pf[ka][fq].w[1] = cvtpk(s[2 * ka][fq][2], s[2 * ka][fq][3]);
        pf[ka][fq].w[2] = cvtpk(s[2 * ka + 1][fq][0], s[2 * ka + 1][fq][1]);
        pf[ka][fq].w[3] = cvtpk(s[2 * ka + 1][fq][2], s[2 * ka + 1][fq][3]);
      }

    // O^T += V^T @ P^T  (swapped operands: C rows = d, cols = q)
    __builtin_amdgcn_s_setprio(1);
#pragma unroll
    for (int ka = 0; ka < 2; ++ka)
#pragma unroll
      for (int fd = 0; fd < 4; ++fd) {
        s16x8 vf = *(const s16x8*)&VsT[(fd * 16 + l15) * 64 + ((ka * 4 + gl) ^ sw) * 8];
#pragma unroll
        for (int qm = 0; qm < 2; ++qm)
          o[qm][fd] = __builtin_amdgcn_mfma_f32_16x16x32_bf16(
              vf, pf[ka][qm].h, o[qm][fd], 0, 0, 0);
      }
    __builtin_amdgcn_s_setprio(0);
  }

  // row-sum reduce: q = fq*16 + l15 (lane-local after reduce)
  float l_[2];
#pragma unroll
  for (int fq = 0; fq < 2; ++fq) {
    float t = (psv[fq][0] + psv[fq][1]) + (psv[fq][2] + psv[fq][3]);
    t += __shfl_xor(t, 16);
    t += __shfl_xor(t, 32);
    l_[fq] = t;
  }
  // store: lane writes 4 consecutive d (row q = qm*16+l15, col d = fd*16+gl*4)
#pragma unroll
  for (int qm = 0; qm < 2; ++qm) {
    const float inv = 1.f / l_[qm];
#pragma unroll
    for (int fd = 0; fd < 4; ++fd) {
      Pk2 p;
      p.w[0] = cvtpk(o[qm][fd][0] * inv, o[qm][fd][1] * inv);
      p.w[1] = cvtpk(o[qm][fd][2] * inv, o[qm][fd][3] * inv);
      *(u16x4*)(CTX + (size_t)(q0 + qm * 16 + l15) * DM + fb + fd * 16 + gl * 4) = p.h;
    }
  }
}

// ---------------------------------------------------------------------------
// Global attention over 16 pooled summaries per batch (fp32, tiny)
// ---------------------------------------------------------------------------
__global__ __launch_bounds__(256)
void gattn(const float* __restrict__ QKVg, u16* __restrict__ GlB)
{
  __shared__ float q[16][64], k[16][64], v[16][64];
  __shared__ float sc[16][16];
  const int bh = blockIdx.x;
  const int b = bh >> 3, h = bh & 7;
  const int tid = threadIdx.x;
  for (int idx = tid; idx < 1024; idx += 256) {
    const int n = idx >> 6, d = idx & 63;
    const size_t off = (size_t)(b * 16 + n) * 1536 + h * 64 + d;
    q[n][d] = QKVg[off]; k[n][d] = QKVg[off + 512]; v[n][d] = QKVg[off + 1024];
  }
  __syncthreads();
  {
    const int qq = tid >> 4, kk = tid & 15;
    float s = 0.f;
#pragma unroll
    for (int d = 0; d < 64; ++d) s = fmaf(q[qq][d], k[kk][d], s);
    sc[qq][kk] = s * SCALE;
  }
  __syncthreads();
  if (tid < 16) {
    float mx = -INFINITY;
#pragma unroll
    for (int j = 0; j < 16; ++j) mx = fmaxf(mx, sc[tid][j]);
    float e[16]; float sum = 0.f;
#pragma unroll
    for (int j = 0; j < 16; ++j) { e[j] = __expf(sc[tid][j] - mx); sum += e[j]; }
    const float inv = 1.f / sum;
#pragma unroll
    for (int j = 0; j < 16; ++j) sc[tid][j] = e[j] * inv;
  }
  __syncthreads();
  for (int idx = tid; idx < 1024; idx += 256) {
    const int qq = idx >> 6, d = idx & 63;
    float o = 0.f;
#pragma unroll
    for (int j = 0; j < 16; ++j) o = fmaf(sc[qq][j], v[j][d], o);
    GlB[(size_t)(b * 16 + qq) * DM + h * 64 + d] = f2b(o);
  }
}

// ---------------------------------------------------------------------------
extern "C" void kernel_launch(void* const* d_in, const int* in_sizes, int n_in,
                              void* d_out, int out_size, void* d_ws, size_t ws_size,
                              hipStream_t stream)
{
  const float* x      = (const float*)d_in[0];
  const float* lq_w   = (const float*)d_in[1];
  const float* lq_b   = (const float*)d_in[2];
  const float* lk_w   = (const float*)d_in[3];
  const float* lk_b   = (const float*)d_in[4];
  const float* lv_w   = (const float*)d_in[5];
  const float* lv_b   = (const float*)d_in[6];
  const float* lo_w   = (const float*)d_in[7];
  const float* lo_b   = (const float*)d_in[8];
  const float* gq_w   = (const float*)d_in[9];
  const float* gq_b   = (const float*)d_in[10];
  const float* gk_w   = (const float*)d_in[11];
  const float* gk_b   = (const float*)d_in[12];
  const float* gv_w   = (const float*)d_in[13];
  const float* gv_b   = (const float*)d_in[14];
  const float* go_w   = (const float*)d_in[15];
  const float* go_b   = (const float*)d_in[16];
  const float* gate_w = (const float*)d_in[17];
  const float* gate_b = (const float*)d_in[18];
  float* out = (float*)d_out;

  const size_t NE = (size_t)NTOK * DM;
  const size_t DD = (size_t)DM * DM;
  char* ws = (char*)d_ws;
  u16* Qb  = (u16*)ws;
  u16* Kb  = Qb + NE;
  u16* VT  = Kb + NE;
  u16* WT  = VT + NE;
  u16* goD = WT + 10 * DD;
  u16* WcT = goD + DD;
  u16* PB  = WcT + DD;
  u16* GlB = PB + 64 * DM;
  float* scr  = (float*)(GlB + 64 * DM);
  float* Psum = scr;
  float* QKVg = Psum + 512 * DM;
  float* GG   = QKVg + (size_t)64 * 1536;
  float* bc   = GG + (size_t)64 * 1024;
  u16* xb = (u16*)d_out;
  u16* LOCAL = Kb;

  u16* WTq  = WT;
  u16* WTk  = WT + 1 * DD;
  u16* WTv  = WT + 2 * DD;
  u16* WTo  = WT + 3 * DD;
  u16* WTg  = WT + 4 * DD;
  u16* WTgq = WT + 5 * DD;
  u16* WTgk = WT + 6 * DD;
  u16* WTgv = WT + 7 * DD;
  u16* WTgo = WT + 8 * DD;
  u16* WTg2 = WT + 9 * DD;

  conv_psum<<<512, 256, 0, stream>>>(x, xb, Psum);
  trans_w<<<dim3(16, 16, 10), 256, 0, stream>>>(
      lq_w, lk_w, lv_w, lo_w, gate_w, gq_w, gk_w, gv_w, go_w,
      gate_w + DD, WT);
  conv_w<<<128, 256, 0, stream>>>(go_w, goD);
  bc_kernel<<<16, 256, 0, stream>>>(go_b, gate_w, gate_b, bc);
  pool_prep<<<64, 256, 0, stream>>>(Psum, PB);

  const dim3 gg(4, 256), bb(256);
  gemm_mfma<0><<<gg, bb, 0, stream>>>(xb, WTq, lq_b, Qb, nullptr, SCLG2E, nullptr);
  gemm_mfma<0><<<gg, bb, 0, stream>>>(xb, WTk, lk_b, Kb, nullptr, 1.0f, nullptr);
  gemm_mfma<2><<<gg, bb, 0, stream>>>(xb, WTv, lv_b, VT, nullptr, 1.0f, nullptr);
  gemm_mfma<3><<<dim3(4, 4), bb, 0, stream>>>(WTg2, goD, nullptr, WcT, nullptr, 1.0f, nullptr);

  attn_mfma<<<dim3(64, 8, 2), 512, 0, stream>>>(Qb, Kb, VT, Qb /*CTX*/);
  gemm_mfma<0><<<gg, bb, 0, stream>>>(Qb /*CTX*/, WTo, lo_b, LOCAL, nullptr, 1.0f, nullptr);

  gemm64<<<12, 256, 0, stream>>>(PB, WTgq, WTgk, WTgv, gq_b, gk_b, gv_b, QKVg, 1536);
  gattn<<<32, 256, 0, stream>>>(QKVg, GlB);
  gemm64<<<8, 256, 0, stream>>>(GlB, WTgo, WcT, WcT, go_b, bc, bc, GG, 1024);

  gemm_mfma<1><<<gg, bb, 0, stream>>>(LOCAL, WTg, nullptr, nullptr, out, 1.0f, GG);
}

// Round 16
// 242.473 us; speedup vs baseline: 1.2963x; 1.0241x over previous
//
#include <hip/hip_runtime.h>
#include <math.h>

typedef unsigned short u16;
typedef short s16;
typedef u16 u16x8 __attribute__((ext_vector_type(8)));
typedef u16 u16x4 __attribute__((ext_vector_type(4)));
typedef s16 s16x8 __attribute__((ext_vector_type(8)));
typedef float f32x4 __attribute__((ext_vector_type(4)));
typedef unsigned u32x4 __attribute__((ext_vector_type(4)));

__device__ __forceinline__ float b2f(u16 u) { return __uint_as_float(((unsigned)u) << 16); }
__device__ __forceinline__ u16 f2b(float f) {
  unsigned x = __float_as_uint(f);
  unsigned r = x + 0x7fffu + ((x >> 16) & 1u);
  return (u16)(r >> 16);
}
__device__ __forceinline__ unsigned cvtpk(float a, float b) {
  unsigned r;
  asm("v_cvt_pk_bf16_f32 %0, %1, %2" : "=v"(r) : "v"(a), "v"(b));
  return r;
}
union PkH { u32x4 w; s16x8 h; };
union Pk2 { unsigned w[2]; u16x4 h; };

#define SCALE 0.125f
#define SCLG2E 0.1803368801111137f   // 0.125 * log2(e); attn uses exp2
#define DM 512
#define NTOK 32768

typedef __attribute__((address_space(1))) unsigned int as1_u32;
typedef __attribute__((address_space(3))) unsigned int as3_u32;
__device__ __forceinline__ void gl2lds16(const u16* g, u16* s) {
  __builtin_amdgcn_global_load_lds((as1_u32*)g, (as3_u32*)s, 16, 0, 0);
}

// ---------------------------------------------------------------------------
// x fp32 -> bf16 + per-64-token column partial sums (for pooled means)
// ---------------------------------------------------------------------------
__global__ __launch_bounds__(256)
void conv_psum(const float* __restrict__ X, u16* __restrict__ Xb,
               float* __restrict__ Psum)
{
  __shared__ float ps[4][512];
  const int tid = threadIdx.x;
  const int c8 = (tid & 63) * 8;
  const int rg = tid >> 6;
  const size_t tok0 = (size_t)blockIdx.x * 64;
  f32x4 s0 = {0.f, 0.f, 0.f, 0.f}, s1 = {0.f, 0.f, 0.f, 0.f};
  for (int it = 0; it < 16; ++it) {
    const size_t tok = tok0 + it * 4 + rg;
    const float* xp = X + tok * DM + c8;
    f32x4 a = *(const f32x4*)xp;
    f32x4 b = *(const f32x4*)(xp + 4);
    Pk2 p0, p1;
    p0.w[0] = cvtpk(a[0], a[1]); p0.w[1] = cvtpk(a[2], a[3]);
    p1.w[0] = cvtpk(b[0], b[1]); p1.w[1] = cvtpk(b[2], b[3]);
    *(u16x4*)(Xb + tok * DM + c8)     = p0.h;
    *(u16x4*)(Xb + tok * DM + c8 + 4) = p1.h;
    s0 += a; s1 += b;
  }
  *(f32x4*)&ps[rg][c8]     = s0;
  *(f32x4*)&ps[rg][c8 + 4] = s1;
  __syncthreads();
#pragma unroll
  for (int i = 0; i < 2; ++i) {
    const int col = tid + i * 256;
    Psum[(size_t)blockIdx.x * DM + col] =
        ps[0][col] + ps[1][col] + ps[2][col] + ps[3][col];
  }
}

// ---------------------------------------------------------------------------
// pooled block means -> bf16
// ---------------------------------------------------------------------------
__global__ __launch_bounds__(256)
void pool_prep(const float* __restrict__ Psum, u16* __restrict__ PB)
{
  const int g = blockIdx.x, tid = threadIdx.x;
#pragma unroll
  for (int i = 0; i < 2; ++i) {
    const int col = tid + i * 256;
    float v = 0.f;
#pragma unroll
    for (int s = 0; s < 8; ++s) v += Psum[(size_t)(g * 8 + s) * DM + col];
    PB[(size_t)g * DM + col] = f2b(v * (1.f / 512.f));
  }
}

// ---------------------------------------------------------------------------
// transpose-convert 10 weight matrices -> Wt [n][k] bf16
// ---------------------------------------------------------------------------
__global__ __launch_bounds__(256)
void trans_w(const float* w0, const float* w1, const float* w2, const float* w3,
             const float* w4, const float* w5, const float* w6, const float* w7,
             const float* w8, const float* w9, u16* __restrict__ WT)
{
  __shared__ float t[32][33];
  const int z = blockIdx.z;
  const float* W = (z == 0) ? w0 : (z == 1) ? w1 : (z == 2) ? w2 : (z == 3) ? w3 :
                   (z == 4) ? w4 : (z == 5) ? w5 : (z == 6) ? w6 : (z == 7) ? w7 :
                   (z == 8) ? w8 : w9;
  u16* D = WT + (size_t)z * DM * DM;
  const int tx = threadIdx.x & 31, ty = threadIdx.x >> 5;
  const int n0 = blockIdx.x * 32, k0 = blockIdx.y * 32;
#pragma unroll
  for (int j = 0; j < 4; ++j)
    t[ty + j * 8][tx] = W[(size_t)(k0 + ty + j * 8) * DM + n0 + tx];
  __syncthreads();
#pragma unroll
  for (int j = 0; j < 4; ++j)
    D[(size_t)(n0 + ty + j * 8) * DM + k0 + tx] = f2b(t[tx][ty + j * 8]);
}

// ---------------------------------------------------------------------------
// direct fp32 -> bf16 convert (go_w)
// ---------------------------------------------------------------------------
__global__ __launch_bounds__(256)
void conv_w(const float* __restrict__ W, u16* __restrict__ D)
{
  const size_t i = ((size_t)blockIdx.x * 256 + threadIdx.x) * 8;
  f32x4 a = *(const f32x4*)(W + i);
  f32x4 b = *(const f32x4*)(W + i + 4);
  Pk2 p0, p1;
  p0.w[0] = cvtpk(a[0], a[1]); p0.w[1] = cvtpk(a[2], a[3]);
  p1.w[0] = cvtpk(b[0], b[1]); p1.w[1] = cvtpk(b[2], b[3]);
  *(u16x4*)(D + i)     = p0.h;
  *(u16x4*)(D + i + 4) = p1.h;
}

// ---------------------------------------------------------------------------
// bc[j] = sum_k go_b[k]*gw2[k][j] + gate_b[j]
// ---------------------------------------------------------------------------
__global__ __launch_bounds__(256)
void bc_kernel(const float* __restrict__ go_b, const float* __restrict__ gate_w,
               const float* __restrict__ gate_b, float* __restrict__ bc)
{
  __shared__ float red[8][32];
  const int tid = threadIdx.x;
  const int jj = tid & 31, part = tid >> 5;
  const int j = blockIdx.x * 32 + jj;
  float p = 0.f;
#pragma unroll
  for (int i = 0; i < 64; ++i) {
    const int k = part * 64 + i;
    p = fmaf(go_b[k], gate_w[(size_t)(512 + k) * DM + j], p);
  }
  red[part][jj] = p;
  __syncthreads();
  if (tid < 32) {
    float v = gate_b[blockIdx.x * 32 + tid];
#pragma unroll
    for (int s = 0; s < 8; ++s) v += red[s][tid];
    bc[blockIdx.x * 32 + tid] = v;
  }
}

// ---------------------------------------------------------------------------
// MFMA GEMM (r12-proven): 128x128 tile, BK=64, 2-phase dbuf, counted vmcnt(8),
// XOR bank swizzle, T1 XCD remap when grid is (4,256).
// EPI 0: Cb = bf16((acc+bias)*outscale)   EPI 1: gate epilogue
// EPI 2: permuted V^T store              EPI 3: Cb = bf16(acc)
// ---------------------------------------------------------------------------
template<int EPI>
__global__ __launch_bounds__(256)
void gemm_mfma(const u16* __restrict__ A, const u16* __restrict__ Wt,
               const float* __restrict__ bias, u16* __restrict__ Cb,
               float* __restrict__ Cf, float outscale,
               const float* __restrict__ GG)
{
  __shared__ u16 As[2][128 * 64];
  __shared__ u16 Bs[2][128 * 64];
  const int tid = threadIdx.x;
  const int w = tid >> 6, l = tid & 63;
  const int l15 = l & 15, gl = l >> 4;
  const int wm = w >> 1, wn = w & 1;

  int mt, nt;
  if (gridDim.y == 256) {           // T1 remap (bijective)
    const int H = blockIdx.y * 4 + blockIdx.x;
    const int xcd = H & 7, i = H >> 3;
    mt = xcd * 32 + (i >> 2);
    nt = i & 3;
  } else {
    mt = blockIdx.y; nt = blockIdx.x;
  }
  const int m0 = mt * 128, n0 = nt * 128;

  const int srow = l >> 3;
  const int scol = ((l & 7) ^ (srow & 7)) * 8;
  const u16* Ag = A  + (size_t)(m0 + w * 32 + srow) * DM + scol;
  const u16* Bg = Wt + (size_t)(n0 + w * 32 + srow) * DM + scol;

  auto stage = [&](int t, int b) {
    const int k0 = t * 64;
#pragma unroll
    for (int c = 0; c < 4; ++c) {
      gl2lds16(Ag + (size_t)(c * 8) * DM + k0, &As[b][(w * 32 + c * 8) * 64]);
      gl2lds16(Bg + (size_t)(c * 8) * DM + k0, &Bs[b][(w * 32 + c * 8) * 64]);
    }
  };

  f32x4 acc[4][4];
#pragma unroll
  for (int i = 0; i < 4; ++i)
#pragma unroll
    for (int j = 0; j < 4; ++j) acc[i][j] = {0.f, 0.f, 0.f, 0.f};

  const int xorv = l15 & 7;
  stage(0, 0);
#pragma unroll
  for (int t = 0; t < 8; ++t) {
    if (t < 7) {
      stage(t + 1, (t + 1) & 1);
      asm volatile("s_waitcnt vmcnt(8)" ::: "memory");
    } else {
      asm volatile("s_waitcnt vmcnt(0)" ::: "memory");
    }
    __builtin_amdgcn_s_barrier();
    __builtin_amdgcn_sched_barrier(0);
    const int b = t & 1;
#pragma unroll
    for (int kd = 0; kd < 2; ++kd) {
      const int go = ((gl + 4 * kd) ^ xorv) * 8;
      s16x8 af[4], bfr[4];
#pragma unroll
      for (int f = 0; f < 4; ++f) {
        af[f]  = *(const s16x8*)&As[b][(wm * 64 + f * 16 + l15) * 64 + go];
        bfr[f] = *(const s16x8*)&Bs[b][(wn * 64 + f * 16 + l15) * 64 + go];
      }
#pragma unroll
      for (int fm = 0; fm < 4; ++fm)
#pragma unroll
        for (int fn = 0; fn < 4; ++fn) {
          if (EPI == 2)
            acc[fm][fn] = __builtin_amdgcn_mfma_f32_16x16x32_bf16(
                af[fm], bfr[fn], acc[fm][fn], 0, 0, 0);
          else
            acc[fm][fn] = __builtin_amdgcn_mfma_f32_16x16x32_bf16(
                bfr[fn], af[fm], acc[fm][fn], 0, 0, 0);
        }
    }
    __builtin_amdgcn_s_barrier();
  }

  if (EPI == 2) {
#pragma unroll
    for (int fn = 0; fn < 4; ++fn) {
      const int n = n0 + wn * 64 + fn * 16 + l15;
      const float bn = bias[n];
      const int d = n & 63, ghn = n >> 6;
#pragma unroll
      for (int fm = 0; fm < 4; ++fm) {
        const int m = m0 + wm * 64 + fm * 16 + gl * 4;
        const int f = (m & 63) >> 4;
        const int pos = ((f >> 1) << 5) | (gl << 3) | ((f & 1) << 2);
        Pk2 p;
        p.w[0] = cvtpk(acc[fm][fn][0] + bn, acc[fm][fn][1] + bn);
        p.w[1] = cvtpk(acc[fm][fn][2] + bn, acc[fm][fn][3] + bn);
        *(u16x4*)(Cb + ((size_t)(((m >> 9) * 8 + ghn) * 64 + d)) * 512
                     + ((m & 511) >> 6) * 64 + pos) = p.h;
      }
    }
  } else {
#pragma unroll
    for (int fm = 0; fm < 4; ++fm) {
      const int m = m0 + wm * 64 + fm * 16 + l15;
      const int brow = m >> 9;
#pragma unroll
      for (int fn = 0; fn < 4; ++fn) {
        const int nb = n0 + wn * 64 + fn * 16 + gl * 4;
        if (EPI == 0) {
          f32x4 b4 = *(const f32x4*)&bias[nb];
          f32x4 v = (acc[fm][fn] + b4) * outscale;
          Pk2 p;
          p.w[0] = cvtpk(v[0], v[1]);
          p.w[1] = cvtpk(v[2], v[3]);
          *(u16x4*)(Cb + (size_t)m * DM + nb) = p.h;
        } else if (EPI == 3) {
          Pk2 p;
          p.w[0] = cvtpk(acc[fm][fn][0], acc[fm][fn][1]);
          p.w[1] = cvtpk(acc[fm][fn][2], acc[fm][fn][3]);
          *(u16x4*)(Cb + (size_t)m * DM + nb) = p.h;
        } else {
          f32x4 z = acc[fm][fn] + *(const f32x4*)&GG[(size_t)brow * 1024 + 512 + nb];
          u16x4 lo4 = *(const u16x4*)(A + (size_t)m * DM + nb);
          f32x4 go4 = *(const f32x4*)&GG[(size_t)brow * 1024 + nb];
          f32x4 res;
#pragma unroll
          for (int r = 0; r < 4; ++r) {
            float g = 1.f / (1.f + __expf(-z[r]));
            res[r] = g * b2f(lo4[r]) + (1.f - g) * go4[r];
          }
          *(f32x4*)(Cf + (size_t)m * DM + nb) = res;
        }
      }
    }
  }
}

// ---------------------------------------------------------------------------
// Small MFMA GEMM (unchanged, validated)
// ---------------------------------------------------------------------------
__global__ __launch_bounds__(256)
void gemm64(const u16* __restrict__ A,
            const u16* B0, const u16* B1, const u16* B2,
            const float* b0, const float* b1, const float* b2,
            float* __restrict__ Out, int ldo)
{
  __shared__ u16 As[2][64 * 64];
  __shared__ u16 Bs[2][128 * 64];
  const int tid = threadIdx.x;
  const int w = tid >> 6, l = tid & 63;
  const int l15 = l & 15, gl = l >> 4;
  const int bx = blockIdx.x;
  const int grp = bx >> 2;
  const u16* Bt = ((grp == 0) ? B0 : (grp == 1) ? B1 : B2)
                  + (size_t)(bx & 3) * 128 * DM;
  const float* bias = (grp == 0) ? b0 : (grp == 1) ? b1 : b2;

  const int srow = l >> 3;
  const int scol = ((l & 7) ^ (srow & 7)) * 8;
  const u16* Ag = A  + (size_t)(w * 16 + srow) * DM + scol;
  const u16* Bg = Bt + (size_t)(w * 32 + srow) * DM + scol;

  auto stage = [&](int t, int b) {
    const int k0 = t * 64;
#pragma unroll
    for (int c = 0; c < 2; ++c)
      gl2lds16(Ag + (size_t)(c * 8) * DM + k0, &As[b][(w * 16 + c * 8) * 64]);
#pragma unroll
    for (int c = 0; c < 4; ++c)
      gl2lds16(Bg + (size_t)(c * 8) * DM + k0, &Bs[b][(w * 32 + c * 8) * 64]);
  };

  f32x4 acc[4][2];
#pragma unroll
  for (int i = 0; i < 4; ++i)
#pragma unroll
    for (int j = 0; j < 2; ++j) acc[i][j] = {0.f, 0.f, 0.f, 0.f};

  const int xorv = l15 & 7;
  stage(0, 0);
#pragma unroll
  for (int t = 0; t < 8; ++t) {
    if (t < 7) {
      stage(t + 1, (t + 1) & 1);
      asm volatile("s_waitcnt vmcnt(6)" ::: "memory");
    } else {
      asm volatile("s_waitcnt vmcnt(0)" ::: "memory");
    }
    __builtin_amdgcn_s_barrier();
    __builtin_amdgcn_sched_barrier(0);
    const int b = t & 1;
#pragma unroll
    for (int kd = 0; kd < 2; ++kd) {
      const int go = ((gl + 4 * kd) ^ xorv) * 8;
      s16x8 af[4], bfr[2];
#pragma unroll
      for (int f = 0; f < 4; ++f)
        af[f] = *(const s16x8*)&As[b][(f * 16 + l15) * 64 + go];
#pragma unroll
      for (int f = 0; f < 2; ++f)
        bfr[f] = *(const s16x8*)&Bs[b][(w * 32 + f * 16 + l15) * 64 + go];
#pragma unroll
      for (int fm = 0; fm < 4; ++fm)
#pragma unroll
        for (int fn = 0; fn < 2; ++fn)
          acc[fm][fn] = __builtin_amdgcn_mfma_f32_16x16x32_bf16(
              bfr[fn], af[fm], acc[fm][fn], 0, 0, 0);
    }
    __builtin_amdgcn_s_barrier();
  }

#pragma unroll
  for (int fm = 0; fm < 4; ++fm) {
    const int m = fm * 16 + l15;
#pragma unroll
    for (int fn = 0; fn < 2; ++fn) {
      const int nloc = w * 32 + fn * 16 + gl * 4;
      f32x4 b4 = *(const f32x4*)&bias[(bx & 3) * 128 + nloc];
      *(f32x4*)&Out[(size_t)m * ldo + bx * 128 + nloc] = acc[fm][fn] + b4;
    }
  }
}

// ---------------------------------------------------------------------------
// MFMA flash attention (r12-validated): no-max exp2 softmax, psv row-sum +
// shfl reduce, XOR-swizzled K/V LDS (0 conflicts), swapped-operand PV with
// vectorized CTX stores and lane-local normalization. No setprio (r15: -8%).
// ---------------------------------------------------------------------------
__global__ __launch_bounds__(512, 4)
void attn_mfma(const u16* __restrict__ Q, const u16* __restrict__ K,
               const u16* __restrict__ VT, u16* __restrict__ CTX)
{
  __shared__ u16 Ks[64 * 64];
  __shared__ u16 VsT[64 * 64];
  const int tid = threadIdx.x;
  const int w = tid >> 6, l = tid & 63;
  const int l15 = l & 15, gl = l >> 4;
  const int g = blockIdx.x, h = blockIdx.y, qh = blockIdx.z;
  const int t0 = g * 512;
  const int fb = h * 64;
  const int q0 = t0 + qh * 256 + w * 32;
  const u16* VTb = VT + ((size_t)(g * 8 + h) * 64) * 512;

  s16x8 qf[2][2];
#pragma unroll
  for (int fq = 0; fq < 2; ++fq)
#pragma unroll
    for (int kd = 0; kd < 2; ++kd)
      qf[fq][kd] = *(const s16x8*)(Q + (size_t)(q0 + fq * 16 + l15) * DM
                                     + fb + gl * 8 + kd * 32);

  f32x4 o[2][4];
#pragma unroll
  for (int i = 0; i < 2; ++i)
#pragma unroll
    for (int j = 0; j < 4; ++j) o[i][j] = {0.f, 0.f, 0.f, 0.f};
  f32x4 psv[2] = {{0.f,0.f,0.f,0.f}, {0.f,0.f,0.f,0.f}};

  const int srow = tid >> 3;
  const int swg = ((tid & 7) ^ ((tid >> 3) & 7)) * 8;
  const u16* Kg = K + (size_t)(t0 + srow) * DM + fb + swg;
  const u16* Vg = VTb + (size_t)srow * 512 + swg;
  s16x8 kreg = *(const s16x8*)Kg;
  s16x8 vreg = *(const s16x8*)Vg;
  const int sw = l15 & 7;

  for (int kc = 0; kc < 8; ++kc) {
    __syncthreads();
    *(s16x8*)&Ks[tid * 8]  = kreg;
    *(s16x8*)&VsT[tid * 8] = vreg;
    __syncthreads();
    if (kc < 7) {
      kreg = *(const s16x8*)(Kg + (size_t)(kc + 1) * 64 * DM);
      vreg = *(const s16x8*)(Vg + (kc + 1) * 64);
    }

    // S^T = K @ Q^T : lane holds S[key=fm*16+gl*4+r][q=fq*16+l15]
    f32x4 s[4][2];
#pragma unroll
    for (int i = 0; i < 4; ++i)
#pragma unroll
      for (int j = 0; j < 2; ++j) s[i][j] = {0.f, 0.f, 0.f, 0.f};
#pragma unroll
    for (int kd = 0; kd < 2; ++kd) {
      s16x8 kf[4];
#pragma unroll
      for (int fm = 0; fm < 4; ++fm)
        kf[fm] = *(const s16x8*)&Ks[(fm * 16 + l15) * 64 + ((gl + 4 * kd) ^ sw) * 8];
#pragma unroll
      for (int fm = 0; fm < 4; ++fm)
#pragma unroll
        for (int fq = 0; fq < 2; ++fq)
          s[fm][fq] = __builtin_amdgcn_mfma_f32_16x16x32_bf16(
              kf[fm], qf[fq][kd], s[fm][fq], 0, 0, 0);
    }

    // P = exp2(S); accumulate row-sum vector (deferred reduce)
#pragma unroll
    for (int fq = 0; fq < 2; ++fq)
#pragma unroll
      for (int fm = 0; fm < 4; ++fm) {
#pragma unroll
        for (int r = 0; r < 4; ++r) s[fm][fq][r] = exp2f(s[fm][fq][r]);
        psv[fq] += s[fm][fq];
      }

    // pack P -> bf16 fragments (keys (2ka+(j>>2))*16+gl*4+(j&3))
    PkH pf[2][2];
#pragma unroll
    for (int ka = 0; ka < 2; ++ka)
#pragma unroll
      for (int fq = 0; fq < 2; ++fq) {
        pf[ka][fq].w[0] = cvtpk(s[2 * ka][fq][0], s[2 * ka][fq][1]);
        pf[ka][fq].w[1] = cvtpk(s[2 * ka][fq][2], s[2 * ka][fq][3]);
        pf[ka][fq].w[2] = cvtpk(s[2 * ka + 1][fq][0], s[2 * ka + 1][fq][1]);
        pf[ka][fq].w[3] = cvtpk(s[2 * ka + 1][fq][2], s[2 * ka + 1][fq][3]);
      }

    // O^T += V^T @ P^T  (swapped operands: C rows = d, cols = q)
#pragma unroll
    for (int ka = 0; ka < 2; ++ka)
#pragma unroll
      for (int fd = 0; fd < 4; ++fd) {
        s16x8 vf = *(const s16x8*)&VsT[(fd * 16 + l15) * 64 + ((ka * 4 + gl) ^ sw) * 8];
#pragma unroll
        for (int qm = 0; qm < 2; ++qm)
          o[qm][fd] = __builtin_amdgcn_mfma_f32_16x16x32_bf16(
              vf, pf[ka][qm].h, o[qm][fd], 0, 0, 0);
      }
  }

  // row-sum reduce: q = fq*16 + l15 (lane-local after reduce)
  float l_[2];
#pragma unroll
  for (int fq = 0; fq < 2; ++fq) {
    float t = (psv[fq][0] + psv[fq][1]) + (psv[fq][2] + psv[fq][3]);
    t += __shfl_xor(t, 16);
    t += __shfl_xor(t, 32);
    l_[fq] = t;
  }
  // store: lane writes 4 consecutive d (row q = qm*16+l15, col d = fd*16+gl*4)
#pragma unroll
  for (int qm = 0; qm < 2; ++qm) {
    const float inv = 1.f / l_[qm];
#pragma unroll
    for (int fd = 0; fd < 4; ++fd) {
      Pk2 p;
      p.w[0] = cvtpk(o[qm][fd][0] * inv, o[qm][fd][1] * inv);
      p.w[1] = cvtpk(o[qm][fd][2] * inv, o[qm][fd][3] * inv);
      *(u16x4*)(CTX + (size_t)(q0 + qm * 16 + l15) * DM + fb + fd * 16 + gl * 4) = p.h;
    }
  }
}

// ---------------------------------------------------------------------------
// Global attention over 16 pooled summaries per batch (fp32, tiny)
// ---------------------------------------------------------------------------
__global__ __launch_bounds__(256)
void gattn(const float* __restrict__ QKVg, u16* __restrict__ GlB)
{
  __shared__ float q[16][64], k[16][64], v[16][64];
  __shared__ float sc[16][16];
  const int bh = blockIdx.x;
  const int b = bh >> 3, h = bh & 7;
  const int tid = threadIdx.x;
  for (int idx = tid; idx < 1024; idx += 256) {
    const int n = idx >> 6, d = idx & 63;
    const size_t off = (size_t)(b * 16 + n) * 1536 + h * 64 + d;
    q[n][d] = QKVg[off]; k[n][d] = QKVg[off + 512]; v[n][d] = QKVg[off + 1024];
  }
  __syncthreads();
  {
    const int qq = tid >> 4, kk = tid & 15;
    float s = 0.f;
#pragma unroll
    for (int d = 0; d < 64; ++d) s = fmaf(q[qq][d], k[kk][d], s);
    sc[qq][kk] = s * SCALE;
  }
  __syncthreads();
  if (tid < 16) {
    float mx = -INFINITY;
#pragma unroll
    for (int j = 0; j < 16; ++j) mx = fmaxf(mx, sc[tid][j]);
    float e[16]; float sum = 0.f;
#pragma unroll
    for (int j = 0; j < 16; ++j) { e[j] = __expf(sc[tid][j] - mx); sum += e[j]; }
    const float inv = 1.f / sum;
#pragma unroll
    for (int j = 0; j < 16; ++j) sc[tid][j] = e[j] * inv;
  }
  __syncthreads();
  for (int idx = tid; idx < 1024; idx += 256) {
    const int qq = idx >> 6, d = idx & 63;
    float o = 0.f;
#pragma unroll
    for (int j = 0; j < 16; ++j) o = fmaf(sc[qq][j], v[j][d], o);
    GlB[(size_t)(b * 16 + qq) * DM + h * 64 + d] = f2b(o);
  }
}

// ---------------------------------------------------------------------------
extern "C" void kernel_launch(void* const* d_in, const int* in_sizes, int n_in,
                              void* d_out, int out_size, void* d_ws, size_t ws_size,
                              hipStream_t stream)
{
  const float* x      = (const float*)d_in[0];
  const float* lq_w   = (const float*)d_in[1];
  const float* lq_b   = (const float*)d_in[2];
  const float* lk_w   = (const float*)d_in[3];
  const float* lk_b   = (const float*)d_in[4];
  const float* lv_w   = (const float*)d_in[5];
  const float* lv_b   = (const float*)d_in[6];
  const float* lo_w   = (const float*)d_in[7];
  const float* lo_b   = (const float*)d_in[8];
  const float* gq_w   = (const float*)d_in[9];
  const float* gq_b   = (const float*)d_in[10];
  const float* gk_w   = (const float*)d_in[11];
  const float* gk_b   = (const float*)d_in[12];
  const float* gv_w   = (const float*)d_in[13];
  const float* gv_b   = (const float*)d_in[14];
  const float* go_w   = (const float*)d_in[15];
  const float* go_b   = (const float*)d_in[16];
  const float* gate_w = (const float*)d_in[17];
  const float* gate_b = (const float*)d_in[18];
  float* out = (float*)d_out;

  const size_t NE = (size_t)NTOK * DM;
  const size_t DD = (size_t)DM * DM;
  char* ws = (char*)d_ws;
  u16* Qb  = (u16*)ws;
  u16* Kb  = Qb + NE;
  u16* VT  = Kb + NE;
  u16* WT  = VT + NE;
  u16* goD = WT + 10 * DD;
  u16* WcT = goD + DD;
  u16* PB  = WcT + DD;
  u16* GlB = PB + 64 * DM;
  float* scr  = (float*)(GlB + 64 * DM);
  float* Psum = scr;
  float* QKVg = Psum + 512 * DM;
  float* GG   = QKVg + (size_t)64 * 1536;
  float* bc   = GG + (size_t)64 * 1024;
  u16* xb = (u16*)d_out;
  u16* LOCAL = Kb;

  u16* WTq  = WT;
  u16* WTk  = WT + 1 * DD;
  u16* WTv  = WT + 2 * DD;
  u16* WTo  = WT + 3 * DD;
  u16* WTg  = WT + 4 * DD;
  u16* WTgq = WT + 5 * DD;
  u16* WTgk = WT + 6 * DD;
  u16* WTgv = WT + 7 * DD;
  u16* WTgo = WT + 8 * DD;
  u16* WTg2 = WT + 9 * DD;

  conv_psum<<<512, 256, 0, stream>>>(x, xb, Psum);
  trans_w<<<dim3(16, 16, 10), 256, 0, stream>>>(
      lq_w, lk_w, lv_w, lo_w, gate_w, gq_w, gk_w, gv_w, go_w,
      gate_w + DD, WT);
  conv_w<<<128, 256, 0, stream>>>(go_w, goD);
  bc_kernel<<<16, 256, 0, stream>>>(go_b, gate_w, gate_b, bc);
  pool_prep<<<64, 256, 0, stream>>>(Psum, PB);

  const dim3 gg(4, 256), bb(256);
  gemm_mfma<0><<<gg, bb, 0, stream>>>(xb, WTq, lq_b, Qb, nullptr, SCLG2E, nullptr);
  gemm_mfma<0><<<gg, bb, 0, stream>>>(xb, WTk, lk_b, Kb, nullptr, 1.0f, nullptr);
  gemm_mfma<2><<<gg, bb, 0, stream>>>(xb, WTv, lv_b, VT, nullptr, 1.0f, nullptr);
  gemm_mfma<3><<<dim3(4, 4), bb, 0, stream>>>(WTg2, goD, nullptr, WcT, nullptr, 1.0f, nullptr);

  attn_mfma<<<dim3(64, 8, 2), 512, 0, stream>>>(Qb, Kb, VT, Qb /*CTX*/);
  gemm_mfma<0><<<gg, bb, 0, stream>>>(Qb /*CTX*/, WTo, lo_b, LOCAL, nullptr, 1.0f, nullptr);

  gemm64<<<12, 256, 0, stream>>>(PB, WTgq, WTgk, WTgv, gq_b, gk_b, gv_b, QKVg, 1536);
  gattn<<<32, 256, 0, stream>>>(QKVg, GlB);
  gemm64<<<8, 256, 0, stream>>>(GlB, WTgo, WcT, WcT, go_b, bc, bc, GG, 1024);

  gemm_mfma<1><<<gg, bb, 0, stream>>>(LOCAL, WTg, nullptr, nullptr, out, 1.0f, GG);
}